// Round 8
// baseline (133.417 us; speedup 1.0000x reference)
//
#include <hip/hip_runtime.h>
#include <stdint.h>

#define B_SZ   512
#define D_SENS 784
#define D_IDX  64
#define D_INT  32
#define D_OUT  10
#define M_ENT  262144
#define NCHUNK (M_ENT / 64)
#define MARGIN 1.5f
#define GRID_F 256

typedef __attribute__((ext_vector_type(8))) short bf16x8;
typedef __attribute__((ext_vector_type(4))) float f32x4;

__device__ inline unsigned short f2bf_rne(float f) {
    unsigned int u = __float_as_uint(f);
    unsigned int r = u + 0x7fffu + ((u >> 16) & 1u);
    return (unsigned short)(r >> 16);
}
// truncation pack (error covered by MARGIN; refine is exact fp32)
__device__ inline unsigned int pack2bf_t(float lo, float hi) {
    return (__float_as_uint(lo) >> 16) | (__float_as_uint(hi) & 0xFFFF0000u);
}

// Device-scope grid barrier. Safe because grid(256) <= residency capacity(512):
// every block is resident, so spin-wait always completes. Counters zeroed by
// hipMemsetAsync each launch. threadfence = cross-XCD release/acquire.
__device__ inline void grid_bar(unsigned int* cnt) {
    __syncthreads();
    if (threadIdx.x == 0) {
        __threadfence();
        unsigned int old = atomicAdd(cnt, 1u);
        unsigned int target = old - (old % GRID_F) + GRID_F;
        while (__hip_atomic_load(cnt, __ATOMIC_RELAXED, __HIP_MEMORY_SCOPE_AGENT) < target)
            __builtin_amdgcn_s_sleep(2);
        __threadfence();
    }
    __syncthreads();
}

struct BackS {
    float a_s[D_IDX];
    float red[256];
    int   list[256];
    int   cnt;
    unsigned long long bestsh;
    float xr[D_SENS];
    float ai[D_INT];
};

// =============== single fused kernel: F -> bar -> S -> bar -> B ===============
__global__ __launch_bounds__(256) void k_fused(
    const float* __restrict__ x, const float* __restrict__ W1, const float* __restrict__ b1,
    const float* __restrict__ W2, const float* __restrict__ b2,
    const float* __restrict__ W3, const float* __restrict__ b3,
    const float* __restrict__ W4, const float* __restrict__ b4,
    const float* __restrict__ keys, const float* __restrict__ mem_values,
    float* __restrict__ a_idx, unsigned short* __restrict__ a_bf,
    float* __restrict__ chunkmin, unsigned int* __restrict__ bar,
    float* __restrict__ out)
{
    __shared__ __align__(16) char smem[81920];   // 80 KB: union of all phases
    int bid = blockIdx.x, tid = threadIdx.x;
    int lane = tid & 63, wid = tid >> 6;

    // ---------------- Phase F: indexer for batch rows 2*bid, 2*bid+1 ----------------
    {
        float* xs = (float*)smem;
        #pragma unroll 1
        for (int bb = 0; bb < 2; ++bb) {
            int b = bid * 2 + bb;
            if (tid < 196) ((float4*)xs)[tid] = ((const float4*)(x + (size_t)b * D_SENS))[tid];
            __syncthreads();
            int i = tid >> 2, sub = tid & 3;
            const float4* wr = (const float4*)(W1 + (size_t)i * D_SENS);
            const float4* xs4 = (const float4*)xs;
            float a0 = 0.f, a1 = 0.f, a2 = 0.f, a3 = 0.f;
            #pragma unroll 7
            for (int jj = 0; jj < 49; ++jj) {
                float4 w = wr[sub + 4 * jj];
                float4 xv = xs4[sub + 4 * jj];
                a0 += w.x * xv.x; a1 += w.y * xv.y; a2 += w.z * xv.z; a3 += w.w * xv.w;
            }
            float s = (a0 + a1) + (a2 + a3);
            s += __shfl_xor(s, 1, 64);
            s += __shfl_xor(s, 2, 64);
            if (sub == 0) {
                float v = s + b1[i];
                float r = v > 0.f ? v : 0.f;
                a_idx[b * D_IDX + i] = r;
                a_bf[b * D_IDX + i] = f2bf_rne(r);
            }
            __syncthreads();
        }
    }
    grid_bar(bar + 0);

    // ---------------- Phase S: MFMA screen, 1024 keys/block in 2 passes ----------------
    {
        unsigned short* qlds = (unsigned short*)smem;          // 64 KB
        float (*cms)[B_SZ] = (float(*)[B_SZ])(smem + 65536);   // 16 KB
        int l15 = lane & 15, lg = lane >> 4;

        // stage all 512 queries once (XOR-swizzled), reused by both passes
        {
            int r = tid >> 3, j = tid & 7;
            #pragma unroll
            for (int pass = 0; pass < 16; ++pass, r += 32) {
                uint4 v = *(const uint4*)((const char*)a_bf + r * 128 + j * 16);
                int boff = r * 128 + ((j * 16) ^ ((r & 7) << 4));
                *(uint4*)((char*)qlds + boff) = v;
            }
        }
        __syncthreads();

        int rsw = (l15 & 7) << 4;
        int r0 = l15 * 128 + ((lg * 16) ^ rsw);
        int r1 = l15 * 128 + ((64 + lg * 16) ^ rsw);

        #pragma unroll 1
        for (int p = 0; p < 2; ++p) {
            int mbase = bid * 1024 + p * 512 + wid * 128;
            bf16x8 kf[8][2];
            f32x4 nrmv[8];
            #pragma unroll
            for (int t = 0; t < 8; ++t) {
                const float* rowp = keys + (size_t)(mbase + 16 * t + l15) * D_IDX;
                float4 f0 = *(const float4*)(rowp + lg * 8);
                float4 f1 = *(const float4*)(rowp + lg * 8 + 4);
                float4 f2 = *(const float4*)(rowp + 32 + lg * 8);
                float4 f3 = *(const float4*)(rowp + 32 + lg * 8 + 4);
                uint4 kp0, kp1;
                kp0.x = pack2bf_t(f0.x, f0.y); kp0.y = pack2bf_t(f0.z, f0.w);
                kp0.z = pack2bf_t(f1.x, f1.y); kp0.w = pack2bf_t(f1.z, f1.w);
                kp1.x = pack2bf_t(f2.x, f2.y); kp1.y = pack2bf_t(f2.z, f2.w);
                kp1.z = pack2bf_t(f3.x, f3.y); kp1.w = pack2bf_t(f3.z, f3.w);
                kf[t][0] = __builtin_bit_cast(bf16x8, kp0);
                kf[t][1] = __builtin_bit_cast(bf16x8, kp1);
                float s = f0.x*f0.x + f0.y*f0.y + f0.z*f0.z + f0.w*f0.w
                        + f1.x*f1.x + f1.y*f1.y + f1.z*f1.z + f1.w*f1.w
                        + f2.x*f2.x + f2.y*f2.y + f2.z*f2.z + f2.w*f2.w
                        + f3.x*f3.x + f3.y*f3.y + f3.z*f3.z + f3.w*f3.w;
                s += __shfl_xor(s, 16, 64);
                s += __shfl_xor(s, 32, 64);
                s *= -0.5f;
                float n0 = __shfl(s, lg * 4 + 0, 64);
                float n1 = __shfl(s, lg * 4 + 1, 64);
                float n2 = __shfl(s, lg * 4 + 2, 64);
                float n3 = __shfl(s, lg * 4 + 3, 64);
                nrmv[t] = (f32x4){n0, n1, n2, n3};
            }

            bf16x8 q0 = *(const bf16x8*)((const char*)qlds + r0);
            bf16x8 q1 = *(const bf16x8*)((const char*)qlds + r1);

            for (int qt = 0; qt < 32; ++qt) {
                bf16x8 c0 = q0, c1 = q1;
                if (qt < 31) {
                    q0 = *(const bf16x8*)((const char*)qlds + r0 + (qt + 1) * 2048);
                    q1 = *(const bf16x8*)((const char*)qlds + r1 + (qt + 1) * 2048);
                }
                f32x4 acc[8];
                #pragma unroll
                for (int t = 0; t < 8; ++t)
                    acc[t] = __builtin_amdgcn_mfma_f32_16x16x32_bf16(kf[t][0], c0, nrmv[t], 0, 0, 0);
                #pragma unroll
                for (int t = 0; t < 8; ++t)
                    acc[t] = __builtin_amdgcn_mfma_f32_16x16x32_bf16(kf[t][1], c1, acc[t], 0, 0, 0);

                #pragma unroll
                for (int h = 0; h < 2; ++h) {
                    int tb = h * 4;
                    float t0 = fmaxf(fmaxf(acc[tb+0][0], acc[tb+0][1]), acc[tb+0][2]);
                    float t1 = fmaxf(fmaxf(acc[tb+0][3], acc[tb+1][0]), acc[tb+1][1]);
                    float t2 = fmaxf(fmaxf(acc[tb+1][2], acc[tb+1][3]), acc[tb+2][0]);
                    float t3 = fmaxf(fmaxf(acc[tb+2][1], acc[tb+2][2]), acc[tb+2][3]);
                    float t4 = fmaxf(fmaxf(acc[tb+3][0], acc[tb+3][1]), acc[tb+3][2]);
                    float mx = fmaxf(fmaxf(fmaxf(t0, t1), fmaxf(t2, t3)), fmaxf(t4, acc[tb+3][3]));
                    mx = fmaxf(mx, __shfl_xor(mx, 16, 64));
                    mx = fmaxf(mx, __shfl_xor(mx, 32, 64));
                    if (lane < 16) cms[wid * 2 + h][qt * 16 + lane] = -2.0f * mx;
                }
            }
            #pragma unroll
            for (int h = 0; h < 2; ++h) {
                int row = wid * 2 + h;
                float4 s0 = *(const float4*)&cms[row][lane * 8];
                float4 s1 = *(const float4*)&cms[row][lane * 8 + 4];
                float4* dst = (float4*)(chunkmin + (size_t)(bid * 16 + p * 8 + row) * B_SZ + lane * 8);
                dst[0] = s0; dst[1] = s1;
            }
            __syncthreads();   // cms reused next pass
        }
    }
    grid_bar(bar + 32);

    // ---------------- Phase B: filter + exact refine + gather + MLP, 2 queries ------
    {
        BackS* bs = (BackS*)smem;
        #pragma unroll 1
        for (int qq = 0; qq < 2; ++qq) {
            int q = bid * 2 + qq;
            if (tid < 16) ((float4*)bs->a_s)[tid] = ((const float4*)(a_idx + q * D_IDX))[tid];
            if (tid == 0) { bs->cnt = 0; bs->bestsh = ~0ULL; }
            __syncthreads();

            float v[16];
            float lm = INFINITY;
            #pragma unroll
            for (int i2 = 0; i2 < 16; ++i2) {
                v[i2] = chunkmin[(size_t)(tid + 256 * i2) * B_SZ + q];
                lm = fminf(lm, v[i2]);
            }
            bs->red[tid] = lm;
            __syncthreads();
            for (int s2 = 128; s2 > 0; s2 >>= 1) {
                if (tid < s2) bs->red[tid] = fminf(bs->red[tid], bs->red[tid + s2]);
                __syncthreads();
            }
            float thrv = bs->red[0] + MARGIN;
            #pragma unroll
            for (int i2 = 0; i2 < 16; ++i2)
                if (v[i2] <= thrv) { int p2 = atomicAdd(&bs->cnt, 1); if (p2 < 256) bs->list[p2] = tid + 256 * i2; }
            __syncthreads();
            int n = bs->cnt > 256 ? 256 : bs->cnt;

            unsigned long long bestp = ~0ULL;
            int kq = tid >> 2, qtr = tid & 3;
            for (int e = 0; e < n; ++e) {
                int m = bs->list[e] * 64 + kq;
                const float4* kp = (const float4*)(keys + (size_t)m * D_IDX + qtr * 16);
                const float4* av = (const float4*)(bs->a_s + qtr * 16);
                float p = 0.f, p2 = 0.f;
                #pragma unroll
                for (int j = 0; j < 4; ++j) {
                    float4 kv = kp[j], a4 = av[j];
                    p  += kv.x * a4.x + kv.y * a4.y + kv.z * a4.z + kv.w * a4.w;
                    p2 += kv.x * kv.x + kv.y * kv.y + kv.z * kv.z + kv.w * kv.w;
                }
                p  += __shfl_xor(p, 1, 64);  p  += __shfl_xor(p, 2, 64);
                p2 += __shfl_xor(p2, 1, 64); p2 += __shfl_xor(p2, 2, 64);
                if (qtr == 0) {
                    float d = p2 - 2.0f * p;
                    unsigned int db = __float_as_uint(d);
                    unsigned int ok = (db & 0x80000000u) ? ~db : (db | 0x80000000u);
                    unsigned long long packed = ((unsigned long long)ok << 32) | (unsigned int)m;
                    bestp = packed < bestp ? packed : bestp;
                }
            }
            #pragma unroll
            for (int off = 32; off >= 1; off >>= 1) {
                unsigned long long o = __shfl_xor(bestp, off, 64);
                bestp = o < bestp ? o : bestp;
            }
            if (lane == 0) atomicMin(&bs->bestsh, bestp);
            __syncthreads();

            unsigned int idx = (unsigned int)(bs->bestsh & 0xFFFFFFFFull);
            if (tid < 196) ((float4*)bs->xr)[tid] = ((const float4*)(mem_values + (size_t)idx * D_SENS))[tid];
            __syncthreads();

            int i = tid >> 3, sub = tid & 7;
            const float* w3r = W3 + (size_t)i * D_SENS;
            float a0 = 0.f, a1 = 0.f, a2 = 0.f, a3 = 0.f;
            #pragma unroll 6
            for (int jj = 0; jj < 24; ++jj) {
                float4 w = *(const float4*)(w3r + sub * 4 + 32 * jj);
                float4 xv = *(const float4*)(bs->xr + sub * 4 + 32 * jj);
                a0 += w.x * xv.x; a1 += w.y * xv.y; a2 += w.z * xv.z; a3 += w.w * xv.w;
            }
            if (sub < 4) {
                float4 w = *(const float4*)(w3r + 768 + sub * 4);
                float4 xv = *(const float4*)(bs->xr + 768 + sub * 4);
                a0 += w.x * xv.x; a1 += w.y * xv.y; a2 += w.z * xv.z; a3 += w.w * xv.w;
            }
            const float* w2r = W2 + (size_t)i * D_IDX;
            #pragma unroll
            for (int jj = 0; jj < 2; ++jj) {
                float4 w = *(const float4*)(w2r + sub * 4 + 32 * jj);
                float4 av = *(const float4*)(bs->a_s + sub * 4 + 32 * jj);
                a0 += w.x * av.x; a1 += w.y * av.y; a2 += w.z * av.z; a3 += w.w * av.w;
            }
            float s = (a0 + a1) + (a2 + a3);
            s += __shfl_xor(s, 1, 64);
            s += __shfl_xor(s, 2, 64);
            s += __shfl_xor(s, 4, 64);
            if (sub == 0) {
                float acc = s + b2[i] + b3[i];
                bs->ai[i] = acc > 0.f ? acc : 0.f;
            }
            __syncthreads();
            if (tid < D_OUT) {
                float acc = b4[tid];
                const float* w4 = W4 + tid * D_INT;
                #pragma unroll
                for (int j = 0; j < D_INT; ++j) acc += w4[j] * bs->ai[j];
                out[q * D_OUT + tid] = acc;
            }
            __syncthreads();
        }
    }
}

// ---------------- Fallback fp32 kernels (proven; only if ws too small) ----------------
__global__ __launch_bounds__(256) void k_front(const float* __restrict__ x,
                                               const float* __restrict__ W1,
                                               const float* __restrict__ b1,
                                               float* __restrict__ a_out,
                                               unsigned short* __restrict__ a_bf,
                                               unsigned long long* __restrict__ best) {
    int b = blockIdx.x, tid = threadIdx.x;
    __shared__ float xs[D_SENS];
    if (tid < 196) ((float4*)xs)[tid] = ((const float4*)(x + (size_t)b * D_SENS))[tid];
    if (tid == 0) best[b] = ~0ULL;
    __syncthreads();
    int i = tid >> 2, sub = tid & 3;
    const float4* wr = (const float4*)(W1 + (size_t)i * D_SENS);
    const float4* xs4 = (const float4*)xs;
    float a0 = 0.f, a1 = 0.f, a2 = 0.f, a3 = 0.f;
    #pragma unroll 7
    for (int jj = 0; jj < 49; ++jj) {
        float4 w = wr[sub + 4 * jj];
        float4 xv = xs4[sub + 4 * jj];
        a0 += w.x * xv.x; a1 += w.y * xv.y; a2 += w.z * xv.z; a3 += w.w * xv.w;
    }
    float s = (a0 + a1) + (a2 + a3);
    s += __shfl_xor(s, 1, 64);
    s += __shfl_xor(s, 2, 64);
    if (sub == 0) {
        float v = s + b1[i];
        float r = v > 0.f ? v : 0.f;
        a_out[b * D_IDX + i] = r;
        a_bf[b * D_IDX + i] = f2bf_rne(r);
    }
}

__global__ void k_norms(const float* __restrict__ keys, float* __restrict__ norms) {
    int m = blockIdx.x * 256 + threadIdx.x;
    const float4* kp = (const float4*)(keys + (size_t)m * D_IDX);
    float a0 = 0.f, a1 = 0.f, a2 = 0.f, a3 = 0.f;
    #pragma unroll
    for (int t = 0; t < 16; t += 4) {
        float4 v0 = kp[t], v1 = kp[t + 1], v2 = kp[t + 2], v3 = kp[t + 3];
        a0 += v0.x * v0.x + v0.y * v0.y + v0.z * v0.z + v0.w * v0.w;
        a1 += v1.x * v1.x + v1.y * v1.y + v1.z * v1.z + v1.w * v1.w;
        a2 += v2.x * v2.x + v2.y * v2.y + v2.z * v2.z + v2.w * v2.w;
        a3 += v3.x * v3.x + v3.y * v3.y + v3.z * v3.z + v3.w * v3.w;
    }
    norms[m] = (a0 + a1) + (a2 + a3);
}

__global__ __launch_bounds__(256) void k_argmin(const float* __restrict__ keys,
                                                const float* __restrict__ norms,
                                                const float* __restrict__ a_idx,
                                                unsigned long long* __restrict__ best) {
    int q = blockIdx.y * 256 + threadIdx.x;
    float a[D_IDX];
    const float4* ap = (const float4*)(a_idx + (size_t)q * D_IDX);
    #pragma unroll
    for (int t = 0; t < 16; ++t) {
        float4 v = ap[t];
        a[4*t+0] = v.x; a[4*t+1] = v.y; a[4*t+2] = v.z; a[4*t+3] = v.w;
    }
    int m0 = blockIdx.x * 512;
    float bestd = INFINITY;
    int besti = 0;
    for (int i = 0; i < 512; ++i) {
        int m = m0 + i;
        const float* kp = keys + (size_t)m * D_IDX;
        float d0 = 0.f, d1 = 0.f, d2 = 0.f, d3 = 0.f;
        #pragma unroll
        for (int j = 0; j < D_IDX; j += 4) {
            d0 += kp[j+0] * a[j+0];
            d1 += kp[j+1] * a[j+1];
            d2 += kp[j+2] * a[j+2];
            d3 += kp[j+3] * a[j+3];
        }
        float dot = (d0 + d1) + (d2 + d3);
        float d = norms[m] - 2.0f * dot;
        if (d < bestd) { bestd = d; besti = m; }
    }
    unsigned int db = __float_as_uint(bestd);
    unsigned int okey = (db & 0x80000000u) ? ~db : (db | 0x80000000u);
    atomicMin(best + q, ((unsigned long long)okey << 32) | (unsigned int)besti);
}

__global__ __launch_bounds__(256) void k_back_fb(const float* __restrict__ keys,
                                                 const float* __restrict__ a_idx,
                                                 const unsigned long long* __restrict__ bestg,
                                                 const float* __restrict__ mem_values,
                                                 const float* __restrict__ W2,
                                                 const float* __restrict__ b2,
                                                 const float* __restrict__ W3,
                                                 const float* __restrict__ b3,
                                                 const float* __restrict__ W4,
                                                 const float* __restrict__ b4,
                                                 float* __restrict__ out) {
    int q = blockIdx.x, tid = threadIdx.x;
    __shared__ float a_s[D_IDX];
    __shared__ float xr[D_SENS];
    __shared__ float ai[D_INT];
    if (tid < 16) ((float4*)a_s)[tid] = ((const float4*)(a_idx + q * D_IDX))[tid];
    __syncthreads();
    unsigned int idx = (unsigned int)(bestg[q] & 0xFFFFFFFFull);
    if (tid < 196) ((float4*)xr)[tid] = ((const float4*)(mem_values + (size_t)idx * D_SENS))[tid];
    __syncthreads();
    int i = tid >> 3, sub = tid & 7;
    const float* w3r = W3 + (size_t)i * D_SENS;
    float a0 = 0.f, a1 = 0.f, a2 = 0.f, a3 = 0.f;
    #pragma unroll 6
    for (int jj = 0; jj < 24; ++jj) {
        float4 w = *(const float4*)(w3r + sub * 4 + 32 * jj);
        float4 xv = *(const float4*)(xr + sub * 4 + 32 * jj);
        a0 += w.x * xv.x; a1 += w.y * xv.y; a2 += w.z * xv.z; a3 += w.w * xv.w;
    }
    if (sub < 4) {
        float4 w = *(const float4*)(w3r + 768 + sub * 4);
        float4 xv = *(const float4*)(xr + 768 + sub * 4);
        a0 += w.x * xv.x; a1 += w.y * xv.y; a2 += w.z * xv.z; a3 += w.w * xv.w;
    }
    const float* w2r = W2 + (size_t)i * D_IDX;
    #pragma unroll
    for (int jj = 0; jj < 2; ++jj) {
        float4 w = *(const float4*)(w2r + sub * 4 + 32 * jj);
        float4 av = *(const float4*)(a_s + sub * 4 + 32 * jj);
        a0 += w.x * av.x; a1 += w.y * av.y; a2 += w.z * av.z; a3 += w.w * av.w;
    }
    float s = (a0 + a1) + (a2 + a3);
    s += __shfl_xor(s, 1, 64);
    s += __shfl_xor(s, 2, 64);
    s += __shfl_xor(s, 4, 64);
    if (sub == 0) {
        float acc = s + b2[i] + b3[i];
        ai[i] = acc > 0.f ? acc : 0.f;
    }
    __syncthreads();
    if (tid < D_OUT) {
        float acc = b4[tid];
        const float* w4 = W4 + tid * D_INT;
        #pragma unroll
        for (int j = 0; j < D_INT; ++j) acc += w4[j] * ai[j];
        out[q * D_OUT + tid] = acc;
    }
}

extern "C" void kernel_launch(void* const* d_in, const int* in_sizes, int n_in,
                              void* d_out, int out_size, void* d_ws, size_t ws_size,
                              hipStream_t stream) {
    const float* x_sensory  = (const float*)d_in[0];
    const float* W1         = (const float*)d_in[1];
    const float* b1         = (const float*)d_in[2];
    const float* W2         = (const float*)d_in[3];
    const float* b2         = (const float*)d_in[4];
    const float* W3         = (const float*)d_in[5];
    const float* b3         = (const float*)d_in[6];
    const float* W4         = (const float*)d_in[7];
    const float* b4         = (const float*)d_in[8];
    const float* mem_keys   = (const float*)d_in[9];
    const float* mem_values = (const float*)d_in[10];
    float* out = (float*)d_out;

    // workspace layout
    char* ws = (char*)d_ws;
    unsigned int*       bar      = (unsigned int*)ws;             // 256 B (2 counters)
    unsigned long long* best     = (unsigned long long*)(ws + 4096);  // 4 KB (fallback)
    float*              a_idx    = (float*)(ws + 8192);           // 128 KB
    unsigned short*     a_bf     = (unsigned short*)(ws + 139264);// 64 KB
    float*              chunkmin = (float*)(ws + 204800);         // 8 MB [chunk][q] (fallback: norms)
    const size_t NEEDED = 204800 + (size_t)NCHUNK * B_SZ * 4;     // ~8.6 MB

    if (ws_size >= NEEDED) {
        hipMemsetAsync(bar, 0, 256, stream);   // zero barrier counters each launch
        k_fused<<<GRID_F, 256, 0, stream>>>(x_sensory, W1, b1, W2, b2, W3, b3, W4, b4,
                                            mem_keys, mem_values, a_idx, a_bf,
                                            chunkmin, bar, out);
    } else {
        float* norms = chunkmin;   // 1 MB within region
        k_front<<<B_SZ, 256, 0, stream>>>(x_sensory, W1, b1, a_idx, a_bf, best);
        k_norms<<<M_ENT / 256, 256, 0, stream>>>(mem_keys, norms);
        k_argmin<<<dim3(M_ENT / 512, 2), 256, 0, stream>>>(mem_keys, norms, a_idx, best);
        k_back_fb<<<B_SZ, 256, 0, stream>>>(mem_keys, a_idx, best, mem_values,
                                            W2, b2, W3, b3, W4, b4, out);
    }
}

// Round 9
// 52.617 us; speedup vs baseline: 2.5356x; 2.5356x over previous
//
#include <hip/hip_runtime.h>
#include <stdint.h>

#define B_SZ   512
#define D_SENS 784
#define D_IDX  64
#define D_INT  32
#define D_OUT  10
#define M_ENT  262144
#define NCHUNK (M_ENT / 64)
#define MARGIN 1.5f

typedef __attribute__((ext_vector_type(8))) short bf16x8;
typedef __attribute__((ext_vector_type(4))) float f32x4;

__device__ inline unsigned short f2bf_rne(float f) {
    unsigned int u = __float_as_uint(f);
    unsigned int r = u + 0x7fffu + ((u >> 16) & 1u);
    return (unsigned short)(r >> 16);
}
// truncation pack (error covered by MARGIN; refine is exact fp32)
__device__ inline unsigned int pack2bf_t(float lo, float hi) {
    return (__float_as_uint(lo) >> 16) | (__float_as_uint(hi) & 0xFFFF0000u);
}

// ---------------- Kernel F: indexer + bf16 copy + best init (proven R7) ----------------
__global__ __launch_bounds__(256) void k_front(const float* __restrict__ x,
                                               const float* __restrict__ W1,
                                               const float* __restrict__ b1,
                                               float* __restrict__ a_out,
                                               unsigned short* __restrict__ a_bf,
                                               unsigned long long* __restrict__ best) {
    int b = blockIdx.x, tid = threadIdx.x;
    __shared__ float xs[D_SENS];
    if (tid < 196) ((float4*)xs)[tid] = ((const float4*)(x + (size_t)b * D_SENS))[tid];
    if (tid == 0) best[b] = ~0ULL;
    __syncthreads();
    int i = tid >> 2, sub = tid & 3;
    const float4* wr = (const float4*)(W1 + (size_t)i * D_SENS);
    const float4* xs4 = (const float4*)xs;
    float a0 = 0.f, a1 = 0.f, a2 = 0.f, a3 = 0.f;
    #pragma unroll 7
    for (int jj = 0; jj < 49; ++jj) {
        float4 w = wr[sub + 4 * jj];
        float4 xv = xs4[sub + 4 * jj];
        a0 += w.x * xv.x; a1 += w.y * xv.y; a2 += w.z * xv.z; a3 += w.w * xv.w;
    }
    float s = (a0 + a1) + (a2 + a3);
    s += __shfl_xor(s, 1, 64);
    s += __shfl_xor(s, 2, 64);
    if (sub == 0) {
        float v = s + b1[i];
        float r = v > 0.f ? v : 0.f;
        a_out[b * D_IDX + i] = r;
        a_bf[b * D_IDX + i] = f2bf_rne(r);
    }
}

// ---------------- Kernel S: MFMA screen (R7) + TRANSPOSED [q][chunk] store ----------
// Block 256 = 4 waves; wave owns 128 keys; queries staged once in swizzled LDS.
// grid 512, 80KB LDS -> 2 blocks/CU. Store change vs R7: block bid owns 8
// consecutive chunks -> per query a 32B contiguous segment at chunkminT[q][bid*8];
// back then reads 16KB fully-coalesced rows (R6-proven filter pattern).
__global__ __launch_bounds__(256) void k_screen(const float* __restrict__ keys,
                                                const unsigned short* __restrict__ ab,
                                                float* __restrict__ chunkminT) {
    __shared__ unsigned short qlds[B_SZ * D_IDX];   // 64 KB
    __shared__ float cms[8][B_SZ];                  // 16 KB
    int tid = threadIdx.x;
    int lane = tid & 63, wid = tid >> 6;
    int l15 = lane & 15, lg = lane >> 4;

    // stage queries: row r (128B), 16B chunk j, XOR-swizzled
    {
        int r = tid >> 3, j = tid & 7;
        #pragma unroll
        for (int pass = 0; pass < 16; ++pass, r += 32) {
            uint4 v = *(const uint4*)((const char*)ab + r * 128 + j * 16);
            int boff = r * 128 + ((j * 16) ^ ((r & 7) << 4));
            *(uint4*)((char*)qlds + boff) = v;
        }
    }

    // 128 keys/wave -> bf16 frags + norms in-register
    int mbase = blockIdx.x * 512 + wid * 128;
    bf16x8 kf[8][2];
    f32x4 nrmv[8];
    #pragma unroll
    for (int t = 0; t < 8; ++t) {
        const float* rowp = keys + (size_t)(mbase + 16 * t + l15) * D_IDX;
        float4 f0 = *(const float4*)(rowp + lg * 8);
        float4 f1 = *(const float4*)(rowp + lg * 8 + 4);
        float4 f2 = *(const float4*)(rowp + 32 + lg * 8);
        float4 f3 = *(const float4*)(rowp + 32 + lg * 8 + 4);
        uint4 kp0, kp1;
        kp0.x = pack2bf_t(f0.x, f0.y); kp0.y = pack2bf_t(f0.z, f0.w);
        kp0.z = pack2bf_t(f1.x, f1.y); kp0.w = pack2bf_t(f1.z, f1.w);
        kp1.x = pack2bf_t(f2.x, f2.y); kp1.y = pack2bf_t(f2.z, f2.w);
        kp1.z = pack2bf_t(f3.x, f3.y); kp1.w = pack2bf_t(f3.z, f3.w);
        kf[t][0] = __builtin_bit_cast(bf16x8, kp0);
        kf[t][1] = __builtin_bit_cast(bf16x8, kp1);
        float s = f0.x*f0.x + f0.y*f0.y + f0.z*f0.z + f0.w*f0.w
                + f1.x*f1.x + f1.y*f1.y + f1.z*f1.z + f1.w*f1.w
                + f2.x*f2.x + f2.y*f2.y + f2.z*f2.z + f2.w*f2.w
                + f3.x*f3.x + f3.y*f3.y + f3.z*f3.z + f3.w*f3.w;
        s += __shfl_xor(s, 16, 64);
        s += __shfl_xor(s, 32, 64);
        s *= -0.5f;
        float n0 = __shfl(s, lg * 4 + 0, 64);
        float n1 = __shfl(s, lg * 4 + 1, 64);
        float n2 = __shfl(s, lg * 4 + 2, 64);
        float n3 = __shfl(s, lg * 4 + 3, 64);
        nrmv[t] = (f32x4){n0, n1, n2, n3};
    }
    __syncthreads();

    int rsw = (l15 & 7) << 4;
    int r0 = l15 * 128 + ((lg * 16) ^ rsw);
    int r1 = l15 * 128 + ((64 + lg * 16) ^ rsw);
    bf16x8 q0 = *(const bf16x8*)((const char*)qlds + r0);
    bf16x8 q1 = *(const bf16x8*)((const char*)qlds + r1);

    for (int qt = 0; qt < 32; ++qt) {
        bf16x8 c0 = q0, c1 = q1;
        if (qt < 31) {
            q0 = *(const bf16x8*)((const char*)qlds + r0 + (qt + 1) * 2048);
            q1 = *(const bf16x8*)((const char*)qlds + r1 + (qt + 1) * 2048);
        }
        f32x4 acc[8];
        #pragma unroll
        for (int t = 0; t < 8; ++t)
            acc[t] = __builtin_amdgcn_mfma_f32_16x16x32_bf16(kf[t][0], c0, nrmv[t], 0, 0, 0);
        #pragma unroll
        for (int t = 0; t < 8; ++t)
            acc[t] = __builtin_amdgcn_mfma_f32_16x16x32_bf16(kf[t][1], c1, acc[t], 0, 0, 0);

        #pragma unroll
        for (int h = 0; h < 2; ++h) {
            int tb = h * 4;
            float t0 = fmaxf(fmaxf(acc[tb+0][0], acc[tb+0][1]), acc[tb+0][2]);
            float t1 = fmaxf(fmaxf(acc[tb+0][3], acc[tb+1][0]), acc[tb+1][1]);
            float t2 = fmaxf(fmaxf(acc[tb+1][2], acc[tb+1][3]), acc[tb+2][0]);
            float t3 = fmaxf(fmaxf(acc[tb+2][1], acc[tb+2][2]), acc[tb+2][3]);
            float t4 = fmaxf(fmaxf(acc[tb+3][0], acc[tb+3][1]), acc[tb+3][2]);
            float mx = fmaxf(fmaxf(fmaxf(t0, t1), fmaxf(t2, t3)), fmaxf(t4, acc[tb+3][3]));
            mx = fmaxf(mx, __shfl_xor(mx, 16, 64));
            mx = fmaxf(mx, __shfl_xor(mx, 32, 64));
            if (lane < 16) cms[wid * 2 + h][qt * 16 + lane] = -2.0f * mx;
        }
    }

    // transposed store: needs all waves' cms rows
    __syncthreads();
    #pragma unroll
    for (int qq = 0; qq < 2; ++qq) {
        int q = tid + qq * 256;
        float4 lo = {cms[0][q], cms[1][q], cms[2][q], cms[3][q]};
        float4 hi = {cms[4][q], cms[5][q], cms[6][q], cms[7][q]};
        float4* dst = (float4*)(chunkminT + (size_t)q * NCHUNK + blockIdx.x * 8);
        dst[0] = lo; dst[1] = hi;
    }
}

// ---------------- Kernel B: coalesced filter + exact refine + gather + MLP ----------
__global__ __launch_bounds__(256) void k_back(const float* __restrict__ chunkminT,
                                              const float* __restrict__ keys,
                                              const float* __restrict__ a_idx,
                                              const unsigned long long* __restrict__ bestg,
                                              const float* __restrict__ mem_values,
                                              const float* __restrict__ W2,
                                              const float* __restrict__ b2,
                                              const float* __restrict__ W3,
                                              const float* __restrict__ b3,
                                              const float* __restrict__ W4,
                                              const float* __restrict__ b4,
                                              float* __restrict__ out) {
    int q = blockIdx.x, tid = threadIdx.x;
    int lane = tid & 63;
    __shared__ float a_s[D_IDX];
    __shared__ float red[256];
    __shared__ int list[256];
    __shared__ int cnt;
    __shared__ unsigned long long bestsh;
    __shared__ float xr[D_SENS];
    __shared__ float ai[D_INT];

    if (tid < 16) ((float4*)a_s)[tid] = ((const float4*)(a_idx + q * D_IDX))[tid];
    if (tid == 0) { cnt = 0; bestsh = ~0ULL; }
    __syncthreads();

    if (chunkminT != nullptr) {
        // ---- phase 1a: filter chunks (fully-coalesced row reads) ----
        const float* wrow = chunkminT + (size_t)q * NCHUNK;
        float v[16];
        float lm = INFINITY;
        #pragma unroll
        for (int i = 0; i < 16; ++i) { v[i] = wrow[tid + 256 * i]; lm = fminf(lm, v[i]); }
        red[tid] = lm;
        __syncthreads();
        for (int s = 128; s > 0; s >>= 1) {
            if (tid < s) red[tid] = fminf(red[tid], red[tid + s]);
            __syncthreads();
        }
        float thrv = red[0] + MARGIN;
        #pragma unroll
        for (int i = 0; i < 16; ++i)
            if (v[i] <= thrv) { int p = atomicAdd(&cnt, 1); if (p < 256) list[p] = tid + 256 * i; }
        __syncthreads();
        int n = cnt > 256 ? 256 : cnt;

        // ---- phase 1b: exact fp32 distances, block-local packed argmin ----
        unsigned long long bestp = ~0ULL;
        int kq = tid >> 2, qtr = tid & 3;
        for (int e = 0; e < n; ++e) {
            int m = list[e] * 64 + kq;
            const float4* kp = (const float4*)(keys + (size_t)m * D_IDX + qtr * 16);
            const float4* av = (const float4*)(a_s + qtr * 16);
            float p = 0.f, p2 = 0.f;
            #pragma unroll
            for (int j = 0; j < 4; ++j) {
                float4 kv = kp[j], a4 = av[j];
                p  += kv.x * a4.x + kv.y * a4.y + kv.z * a4.z + kv.w * a4.w;
                p2 += kv.x * kv.x + kv.y * kv.y + kv.z * kv.z + kv.w * kv.w;
            }
            p  += __shfl_xor(p, 1, 64);  p  += __shfl_xor(p, 2, 64);
            p2 += __shfl_xor(p2, 1, 64); p2 += __shfl_xor(p2, 2, 64);
            if (qtr == 0) {
                float d = p2 - 2.0f * p;
                unsigned int db = __float_as_uint(d);
                unsigned int ok = (db & 0x80000000u) ? ~db : (db | 0x80000000u);
                unsigned long long packed = ((unsigned long long)ok << 32) | (unsigned int)m;
                bestp = packed < bestp ? packed : bestp;
            }
        }
        #pragma unroll
        for (int off = 32; off >= 1; off >>= 1) {
            unsigned long long o = __shfl_xor(bestp, off, 64);
            bestp = o < bestp ? o : bestp;
        }
        if (lane == 0) atomicMin(&bestsh, bestp);
        __syncthreads();
    } else {
        if (tid == 0) bestsh = bestg[q];
        __syncthreads();
    }

    // ---- phase 2: gather + integrator + output ----
    unsigned int idx = (unsigned int)(bestsh & 0xFFFFFFFFull);
    if (tid < 196) ((float4*)xr)[tid] = ((const float4*)(mem_values + (size_t)idx * D_SENS))[tid];
    __syncthreads();

    int i = tid >> 3, sub = tid & 7;
    const float* w3r = W3 + (size_t)i * D_SENS;
    float a0 = 0.f, a1 = 0.f, a2 = 0.f, a3 = 0.f;
    #pragma unroll 6
    for (int jj = 0; jj < 24; ++jj) {
        float4 w = *(const float4*)(w3r + sub * 4 + 32 * jj);
        float4 xv = *(const float4*)(xr + sub * 4 + 32 * jj);
        a0 += w.x * xv.x; a1 += w.y * xv.y; a2 += w.z * xv.z; a3 += w.w * xv.w;
    }
    if (sub < 4) {
        float4 w = *(const float4*)(w3r + 768 + sub * 4);
        float4 xv = *(const float4*)(xr + 768 + sub * 4);
        a0 += w.x * xv.x; a1 += w.y * xv.y; a2 += w.z * xv.z; a3 += w.w * xv.w;
    }
    const float* w2r = W2 + (size_t)i * D_IDX;
    #pragma unroll
    for (int jj = 0; jj < 2; ++jj) {
        float4 w = *(const float4*)(w2r + sub * 4 + 32 * jj);
        float4 av = *(const float4*)(a_s + sub * 4 + 32 * jj);
        a0 += w.x * av.x; a1 += w.y * av.y; a2 += w.z * av.z; a3 += w.w * av.w;
    }
    float s = (a0 + a1) + (a2 + a3);
    s += __shfl_xor(s, 1, 64);
    s += __shfl_xor(s, 2, 64);
    s += __shfl_xor(s, 4, 64);
    if (sub == 0) {
        float acc = s + b2[i] + b3[i];
        ai[i] = acc > 0.f ? acc : 0.f;
    }
    __syncthreads();
    if (tid < D_OUT) {
        float acc = b4[tid];
        const float* w4 = W4 + tid * D_INT;
        #pragma unroll
        for (int j = 0; j < D_INT; ++j) acc += w4[j] * ai[j];
        out[q * D_OUT + tid] = acc;
    }
}

// ---------------- Fallback fp32 kernels (proven) ----------------
__global__ void k_norms(const float* __restrict__ keys, float* __restrict__ norms) {
    int m = blockIdx.x * 256 + threadIdx.x;
    const float4* kp = (const float4*)(keys + (size_t)m * D_IDX);
    float a0 = 0.f, a1 = 0.f, a2 = 0.f, a3 = 0.f;
    #pragma unroll
    for (int t = 0; t < 16; t += 4) {
        float4 v0 = kp[t], v1 = kp[t + 1], v2 = kp[t + 2], v3 = kp[t + 3];
        a0 += v0.x * v0.x + v0.y * v0.y + v0.z * v0.z + v0.w * v0.w;
        a1 += v1.x * v1.x + v1.y * v1.y + v1.z * v1.z + v1.w * v1.w;
        a2 += v2.x * v2.x + v2.y * v2.y + v2.z * v2.z + v2.w * v2.w;
        a3 += v3.x * v3.x + v3.y * v3.y + v3.z * v3.z + v3.w * v3.w;
    }
    norms[m] = (a0 + a1) + (a2 + a3);
}

__global__ __launch_bounds__(256) void k_argmin(const float* __restrict__ keys,
                                                const float* __restrict__ norms,
                                                const float* __restrict__ a_idx,
                                                unsigned long long* __restrict__ best) {
    int q = blockIdx.y * 256 + threadIdx.x;
    float a[D_IDX];
    const float4* ap = (const float4*)(a_idx + (size_t)q * D_IDX);
    #pragma unroll
    for (int t = 0; t < 16; ++t) {
        float4 v = ap[t];
        a[4*t+0] = v.x; a[4*t+1] = v.y; a[4*t+2] = v.z; a[4*t+3] = v.w;
    }
    int m0 = blockIdx.x * 512;
    float bestd = INFINITY;
    int besti = 0;
    for (int i = 0; i < 512; ++i) {
        int m = m0 + i;
        const float* kp = keys + (size_t)m * D_IDX;
        float d0 = 0.f, d1 = 0.f, d2 = 0.f, d3 = 0.f;
        #pragma unroll
        for (int j = 0; j < D_IDX; j += 4) {
            d0 += kp[j+0] * a[j+0];
            d1 += kp[j+1] * a[j+1];
            d2 += kp[j+2] * a[j+2];
            d3 += kp[j+3] * a[j+3];
        }
        float dot = (d0 + d1) + (d2 + d3);
        float d = norms[m] - 2.0f * dot;
        if (d < bestd) { bestd = d; besti = m; }
    }
    unsigned int db = __float_as_uint(bestd);
    unsigned int okey = (db & 0x80000000u) ? ~db : (db | 0x80000000u);
    atomicMin(best + q, ((unsigned long long)okey << 32) | (unsigned int)besti);
}

extern "C" void kernel_launch(void* const* d_in, const int* in_sizes, int n_in,
                              void* d_out, int out_size, void* d_ws, size_t ws_size,
                              hipStream_t stream) {
    const float* x_sensory  = (const float*)d_in[0];
    const float* W1         = (const float*)d_in[1];
    const float* b1         = (const float*)d_in[2];
    const float* W2         = (const float*)d_in[3];
    const float* b2         = (const float*)d_in[4];
    const float* W3         = (const float*)d_in[5];
    const float* b3         = (const float*)d_in[6];
    const float* W4         = (const float*)d_in[7];
    const float* b4         = (const float*)d_in[8];
    const float* mem_keys   = (const float*)d_in[9];
    const float* mem_values = (const float*)d_in[10];
    float* out = (float*)d_out;

    // workspace layout
    char* ws = (char*)d_ws;
    unsigned long long* best      = (unsigned long long*)ws;         // 4 KB @ 0
    float*              a_idx     = (float*)(ws + 4096);             // 128 KB
    unsigned short*     a_bf      = (unsigned short*)(ws + 135168);  // 64 KB
    float*              chunkminT = (float*)(ws + 200704);           // 8 MB [q][chunk]
    const size_t NEEDED = 200704 + (size_t)B_SZ * NCHUNK * 4;        // ~8.6 MB

    if (ws_size >= NEEDED) {
        k_front<<<B_SZ, 256, 0, stream>>>(x_sensory, W1, b1, a_idx, a_bf, best);
        k_screen<<<M_ENT / 512, 256, 0, stream>>>(mem_keys, a_bf, chunkminT);
        k_back<<<B_SZ, 256, 0, stream>>>(chunkminT, mem_keys, a_idx, nullptr, mem_values,
                                         W2, b2, W3, b3, W4, b4, out);
    } else {
        // fallback: fp32 brute-force path (~1.2 MB)
        float* norms = (float*)(ws + 200704);
        k_front<<<B_SZ, 256, 0, stream>>>(x_sensory, W1, b1, a_idx, a_bf, best);
        k_norms<<<M_ENT / 256, 256, 0, stream>>>(mem_keys, norms);
        k_argmin<<<dim3(M_ENT / 512, 2), 256, 0, stream>>>(mem_keys, norms, a_idx, best);
        k_back<<<B_SZ, 256, 0, stream>>>(nullptr, mem_keys, a_idx, best, mem_values,
                                         W2, b2, W3, b3, W4, b4, out);
    }
}